// Round 18
// baseline (110.519 us; speedup 1.0000x reference)
//
#include <hip/hip_runtime.h>
#include <hip/hip_bf16.h>

typedef __attribute__((ext_vector_type(8))) short short8;
typedef __attribute__((ext_vector_type(4))) short short4v;
typedef __attribute__((ext_vector_type(4))) float f32x4;

#define D_MODEL 1024
#define N_HEADS 16
#define D_KK 64
#define BATCH 4
#define SEQ 1024
#define NTOK (BATCH*SEQ)

#define LOG2E  1.44269504f
#define SCALE2 (0.125f * 1.44269504f)
#define NEGBIG (-1.44269504e9f)

#if __has_builtin(__builtin_amdgcn_mfma_f32_16x16x16bf16_1k)
#define HAVE_MFMA16 1
#else
#define HAVE_MFMA16 0
#endif

#if __has_builtin(__builtin_amdgcn_exp2f)
#define EXP2(x) __builtin_amdgcn_exp2f(x)
#else
#define EXP2(x) exp2f(x)
#endif

template<int N> struct ic { static constexpr int value = N; };

// round-to-nearest-even f32 -> bf16 (bit pattern in short)
__device__ __forceinline__ short f2b(float f){
  unsigned u = __float_as_uint(f);
  u += 0x7fffu + ((u >> 16) & 1u);
  return (short)(u >> 16);
}

__device__ __forceinline__ void gl2lds16(const void* g, void* l){
  __builtin_amdgcn_global_load_lds(
      (const __attribute__((address_space(1))) void*)g,
      (__attribute__((address_space(3))) void*)l, 16, 0, 0);
}

__device__ __forceinline__ float max3f(float a, float b, float c){
  float d; asm("v_max3_f32 %0, %1, %2, %3" : "=v"(d) : "v"(a), "v"(b), "v"(c)); return d;
}
__device__ __forceinline__ float tmax16(const f32x4* sc){
  float t = max3f(sc[0][0], sc[0][1], sc[0][2]);
  t = max3f(t, sc[0][3], sc[1][0]);
  t = max3f(t, sc[1][1], sc[1][2]);
  t = max3f(t, sc[1][3], sc[2][0]);
  t = max3f(t, sc[2][1], sc[2][2]);
  t = max3f(t, sc[2][3], sc[3][0]);
  t = max3f(t, sc[3][1], sc[3][2]);
  return fmaxf(t, sc[3][3]);
}

// ---------------- fused f32 -> bf16 conversion (x, wq, wk, wv, wo) ----------
__global__ __launch_bounds__(256) void cvt_all_kernel(
    const float* __restrict__ x,  const float* __restrict__ wq,
    const float* __restrict__ wk, const float* __restrict__ wv,
    const float* __restrict__ wo, short* __restrict__ dst)
{
  const size_t NX = (size_t)NTOK * D_MODEL;
  const size_t NW = (size_t)D_MODEL * D_MODEL;
  size_t e = ((size_t)blockIdx.x * 256 + threadIdx.x) * 4;
  const float* s;
  size_t off;
  if      (e < NX)        { s = x;  off = e; }
  else if (e < NX +   NW) { s = wq; off = e - NX; }
  else if (e < NX + 2*NW) { s = wk; off = e - NX -   NW; }
  else if (e < NX + 3*NW) { s = wv; off = e - NX - 2*NW; }
  else                    { s = wo; off = e - NX - 3*NW; }
  f32x4 v = *reinterpret_cast<const f32x4*>(s + off);
  short4v o;
  o[0]=f2b(v[0]); o[1]=f2b(v[1]); o[2]=f2b(v[2]); o[3]=f2b(v[3]);
  *reinterpret_cast<short4v*>(dst + e) = o;
}

// ---------------- z-fused QKV GEMM, double-buffered + counted vmcnt --------
// 512 blocks x 256 thr, XCD-grouped, tile 128x64, 4 waves (2x2, 64x32 each).
// A staged once per K-step, reused for Wq/Wk/Wv (48 MFMA/wave/barrier-pair).
// Round 18: As/Bs double-buffered, raw s_barrier + vmcnt(10) (10 wave-uniform
// loads per stage: 4 A + 6 B) — prefetch stays in flight across barriers
// instead of being drained by __syncthreads' vmcnt(0).
__global__ __launch_bounds__(256) void qkv_gemm_kernel(
    const short* __restrict__ X,
    const short* __restrict__ Wq, const short* __restrict__ Wk, const short* __restrict__ Wv,
    const float* __restrict__ bq, const float* __restrict__ bk, const float* __restrict__ bv,
    short* __restrict__ Q, short* __restrict__ K, short* __restrict__ V)
{
  __shared__ short As[2][128*64];      // 32 KB
  __shared__ short Bs[2][3][64*64];    // 48 KB
  const int bid = blockIdx.x;
  const int xcd = bid & 7, s = bid >> 3;        // s in [0,64)
  const int bn0 = (s >> 2) * 64;                 // 16 N-tiles
  const int bm0 = (xcd * 4 + (s & 3)) * 128;     // 4 M-tiles per XCD

  const int tid = threadIdx.x, lane = tid & 63, w = tid >> 6;
  const int wr = w >> 1, wc = w & 1;             // wave-tile 64x32
  const int srow = lane >> 3;
  const int scol = ((lane & 7) ^ srow) * 8;
  const int fr = lane & 15, g = lane >> 4;

  const short* const Wz[3] = {Wq, Wk, Wv};

  f32x4 acc[3][4][2];
  #pragma unroll
  for (int z=0;z<3;z++)
    #pragma unroll
    for (int m=0;m<4;m++)
      #pragma unroll
      for (int n=0;n<2;n++) acc[z][m][n] = (f32x4){0.f,0.f,0.f,0.f};

  // wave-uniform: exactly 10 global_load_lds per stage call
  auto stage = [&](int buf, int t){
    const int k0 = t * 64;
    #pragma unroll
    for (int i=0;i<4;i++){
      const int c = w*4 + i;
      gl2lds16(X + (size_t)(bm0 + c*8 + srow)*D_MODEL + k0 + scol, &As[buf][c*8*64]);
    }
    #pragma unroll
    for (int z=0;z<3;z++)
      #pragma unroll
      for (int i=0;i<2;i++){
        const int c = w*2 + i;
        gl2lds16(Wz[z] + (size_t)(bn0 + c*8 + srow)*D_MODEL + k0 + scol, &Bs[buf][z][c*8*64]);
      }
  };

  auto kstep = [&](auto BUFC, auto VMC) __attribute__((always_inline)) {
    constexpr int BUFL = decltype(BUFC)::value;
    constexpr int VM   = decltype(VMC)::value;
    if constexpr (VM == 10) asm volatile("s_waitcnt vmcnt(10)" ::: "memory");
    else                    asm volatile("s_waitcnt vmcnt(0)"  ::: "memory");
    __builtin_amdgcn_s_barrier();
    asm volatile("" ::: "memory");
    #pragma unroll
    for (int f=0; f<2; f++){
      short8 af[4];
      #pragma unroll
      for (int m=0;m<4;m++){
        const int rr = wr*64 + m*16 + fr;
        af[m] = *reinterpret_cast<const short8*>(
            (const char*)&As[BUFL][0] + rr*128 + ((g*16 + f*64) ^ ((rr&7)<<4)));
      }
      #pragma unroll
      for (int z=0;z<3;z++){
        short8 bfr[2];
        #pragma unroll
        for (int n=0;n<2;n++){
          const int rr = wc*32 + n*16 + fr;
          bfr[n] = *reinterpret_cast<const short8*>(
              (const char*)&Bs[BUFL][z][0] + rr*128 + ((g*16 + f*64) ^ ((rr&7)<<4)));
        }
        #pragma unroll
        for (int m=0;m<4;m++)
          #pragma unroll
          for (int n=0;n<2;n++)
            acc[z][m][n] = __builtin_amdgcn_mfma_f32_16x16x32_bf16(af[m], bfr[n], acc[z][m][n], 0,0,0);
      }
    }
    asm volatile("" ::: "memory");
    __builtin_amdgcn_s_barrier();
  };

  stage(0, 0);
  stage(1, 1);
  for (int t = 0; t < 14; t += 2){       // t = 0,2,...,12
    kstep(ic<0>{}, ic<10>{});            // tile t
    stage(0, t+2);                       // t+2 <= 14
    kstep(ic<1>{}, ic<10>{});            // tile t+1
    stage(1, t+3);                       // t+3 <= 15
  }
  kstep(ic<0>{}, ic<10>{});              // tile 14 (S15 still in flight)
  kstep(ic<1>{}, ic<0>{});               // tile 15 (drain)

  // epilogue: z=0 -> Q (prescaled), z=1 -> K, z=2 -> V transposed per head
  #pragma unroll
  for (int z=0;z<3;z++){
    const float* bias = (z==0) ? bq : (z==1) ? bk : bv;
    #pragma unroll
    for (int n=0;n<2;n++){
      const int col = bn0 + wc*32 + n*16 + fr;
      const float bv_ = bias[col];
      #pragma unroll
      for (int m=0;m<4;m++){
        const int row0 = bm0 + wr*64 + m*16 + g*4;
        if (z == 2){
          const int hh = col >> 6, dd = col & 63;
          const int bb = row0 >> 10, ss = row0 & 1023;
          short4v o;
          #pragma unroll
          for (int r=0;r<4;r++) o[r] = f2b(acc[z][m][n][r] + bv_);
          *reinterpret_cast<short4v*>(
              V + ((size_t)(bb*N_HEADS+hh)*D_KK + dd)*SEQ + ss) = o;
        } else {
          short* O = (z==0) ? Q : K;
          #pragma unroll
          for (int r=0;r<4;r++){
            float v = acc[z][m][n][r] + bv_;
            if (z == 0) v *= SCALE2;
            O[(size_t)(row0+r)*D_MODEL + col] = f2b(v);
          }
        }
      }
    }
  }
}

// ---------------- GEMM body, 4-wave (out_gemm) ----------------------------
template<int BN, int MODE, bool PRESC>
__device__ __forceinline__ void gemm_bt_body(const short* __restrict__ A,
    const short* __restrict__ W, const float* __restrict__ bias,
    void* __restrict__ Cout, int N, int K, int bm0, int bn0,
    short* AsB, short* BsB)
{
  constexpr int NF = BN / 32;
  const int tid = threadIdx.x, lane = tid & 63, w = tid >> 6;
  const int wr = w >> 1, wc = w & 1;
  const int srow = lane >> 3;
  const int scol = ((lane & 7) ^ srow) * 8;
  const int fr = lane & 15, g = lane >> 4;

  f32x4 acc[4][NF];
  #pragma unroll
  for (int m=0;m<4;m++)
    #pragma unroll
    for (int n=0;n<NF;n++) acc[m][n] = (f32x4){0.f,0.f,0.f,0.f};

  for (int k0 = 0; k0 < K; k0 += 64){
    __syncthreads();
    #pragma unroll
    for (int i=0;i<4;i++){
      const int c = w*4 + i;
      gl2lds16(A + (size_t)(bm0 + c*8 + srow)*K + k0 + scol, &AsB[c*8*64]);
    }
    #pragma unroll
    for (int i=0;i<NF;i++){
      const int c = w*NF + i;
      gl2lds16(W + (size_t)(bn0 + c*8 + srow)*K + k0 + scol, &BsB[c*8*64]);
    }
    __syncthreads();
    #pragma unroll
    for (int f=0; f<2; f++){
      short8 af[4], bfr[NF];
      #pragma unroll
      for (int m=0;m<4;m++){
        const int rr = wr*64 + m*16 + fr;
        af[m] = *reinterpret_cast<const short8*>(
            (const char*)AsB + rr*128 + ((g*16 + f*64) ^ ((rr&7)<<4)));
      }
      #pragma unroll
      for (int n=0;n<NF;n++){
        const int rr = wc*(BN/2) + n*16 + fr;
        bfr[n] = *reinterpret_cast<const short8*>(
            (const char*)BsB + rr*128 + ((g*16 + f*64) ^ ((rr&7)<<4)));
      }
      #pragma unroll
      for (int m=0;m<4;m++)
        #pragma unroll
        for (int n=0;n<NF;n++)
          acc[m][n] = __builtin_amdgcn_mfma_f32_16x16x32_bf16(af[m], bfr[n], acc[m][n], 0,0,0);
    }
  }

  #pragma unroll
  for (int n=0;n<NF;n++){
    const int col = bn0 + wc*(BN/2) + n*16 + fr;
    const float bv = bias[col];
    #pragma unroll
    for (int m=0;m<4;m++){
      const int row0 = bm0 + wr*64 + m*16 + g*4;
      #pragma unroll
      for (int r=0;r<4;r++){
        float v = acc[m][n][r] + bv;
        if (PRESC) v *= SCALE2;
        if (MODE == 1) ((float*)Cout)[(size_t)(row0+r)*N + col] = v;
        else           ((short*)Cout)[(size_t)(row0+r)*N + col] = f2b(v);
      }
    }
  }
}

// 512 blocks x 256 threads, XCD-grouped.
__global__ __launch_bounds__(256) void out_gemm_kernel(
    const short* __restrict__ Ctx, const short* __restrict__ Wo,
    const float* __restrict__ bo, float* __restrict__ Out)
{
  __shared__ short As[128*64];
  __shared__ short Bs[64*64];
  const int bid = blockIdx.x;
  const int xcd = bid & 7, s = bid >> 3;   // s in [0,64)
  const int bn0 = (s >> 2) * 64;            // 16 N-tiles
  const int bm0 = (xcd * 4 + (s & 3)) * 128;
  gemm_bt_body<64,1,false>(Ctx, Wo, bo, Out, D_MODEL, D_MODEL, bm0, bn0, As, Bs);
}

// ---------------- flash attention (unchanged from round 15) ---------------
__global__ __launch_bounds__(512, 2) void attn_kernel(
    const short* __restrict__ Qb, const short* __restrict__ Kb,
    const short* __restrict__ Vtg, const int* __restrict__ mask,
    const float* __restrict__ rel_table, short* __restrict__ Ctx)
{
  const int bid = blockIdx.x;
  const int xcd = bid & 7, slot = bid >> 3;
  const int bh = xcd * 8 + (slot >> 3);      // 8 (b,h) groups per XCD
  const int qt = slot & 7;                   // 8 q-tiles of 128 rows
  const int b = bh >> 4, h = bh & 15;
  const int q0 = qt * 128;
  const int tid = threadIdx.x, lane = tid & 63, w = tid >> 6;
  const int team = w >> 2, wt = w & 3;
  const int fr = lane & 15, g = lane >> 4;

  __shared__ short kvbuf[2][2][2][64][64];  // [K/V][team][buf][row][64], swizzled
  __shared__ float rel_pad[384];            // rel*log2e, clamp baked, offset +128
  __shared__ float mb_all[2][8][64];        // per-team per-tile mask+cb bias
  __shared__ float ml[128][2];

  for (int i = tid; i < 384; i += 512){
    int d = i - 128;
    d = d < 0 ? 0 : (d > 126 ? 126 : d);
    rel_pad[i] = rel_table[d * N_HEADS + h] * LOG2E;
  }
  const float cb_lo = rel_table[0*N_HEADS + h]   * LOG2E;
  const float cb_hi = rel_table[126*N_HEADS + h] * LOG2E;

  for (int e = tid; e < 1024; e += 512){
    const int tm = e >> 9, tt = (e >> 6) & 7, i = e & 63;
    const int kvt = tm*512 + tt*64;
    const int delta = kvt - q0;
    const bool far = (delta <= -128 || delta >= 192);
    const float cb = far ? (delta > 0 ? cb_hi : cb_lo) : 0.f;
    mb_all[tm][tt][i] = mask[b*SEQ + kvt + i] ? cb : NEGBIG;
  }

  const short* Qg = Qb + (size_t)b*SEQ*D_MODEL + h*D_KK;
  const short* Kg = Kb + (size_t)b*SEQ*D_MODEL + h*D_KK;
  const short* Vg = Vtg + (size_t)bh*D_KK*SEQ;

  const int qa = q0 + wt*32 + fr;
  const int qb = qa + 16;
  short8 qfa[2], qfb[2];
  #pragma unroll
  for (int f=0; f<2; f++){
    qfa[f] = *reinterpret_cast<const short8*>(Qg + (size_t)qa*D_MODEL + g*8 + f*32);
    qfb[f] = *reinterpret_cast<const short8*>(Qg + (size_t)qb*D_MODEL + g*8 + f*32);
  }

  const char* lds0 = (const char*)kvbuf;
  const int swzb = (fr & 7) << 4;
  const char* kp[2];
  #pragma unroll
  for (int f=0; f<2; f++)
    kp[f] = lds0 + team*16384 + fr*128 + ((g*16 + f*64) ^ swzb);
  const char* vp[4];
  #pragma unroll
  for (int kt=0; kt<4; kt++)
    vp[kt] = lds0 + 32768 + team*16384 + fr*128
           + ((((kt*2 + (g>>1)) ^ (fr&7)) << 4) + (g&1)*8);
  const char* mbp0 = (const char*)mb_all + team*2048 + g*16;

  f32x4 ctxa[4], ctxb[4];
  #pragma unroll
  for (int dt=0; dt<4; dt++){ ctxa[dt] = (f32x4){0.f,0.f,0.f,0.f}; ctxb[dt] = ctxa[dt]; }
  float mruna = -3.0e38f, lruna = 0.f, mrunb = -3.0e38f, lrunb = 0.f;

  const int srow = lane >> 3;
  const int scol = ((lane & 7) ^ srow) * 8;
  auto stage = [&](int buf, int kv0){
    #pragma unroll
    for (int i=0;i<2;i++){
      const int c = wt*2 + i;
      gl2lds16(Kg + (size_t)(kv0 + c*8 + srow)*D_MODEL + scol, &kvbuf[0][team][buf][c*8][0]);
      gl2lds16(Vg + (size_t)(c*8 + srow)*SEQ + kv0 + scol,     &kvbuf[1][team][buf][c*8][0]);
    }
  };

  auto tile_step = [&](auto BUFC, auto VMC, int kv0, int tt) __attribute__((always_inline)) {
    constexpr int BUFL = decltype(BUFC)::value;
    constexpr int VM   = decltype(VMC)::value;

    if constexpr (VM == 4) asm volatile("s_waitcnt vmcnt(4)" ::: "memory");
    else                   asm volatile("s_waitcnt vmcnt(0)" ::: "memory");
    __builtin_amdgcn_s_barrier();
    asm volatile("" ::: "memory");

    const char* mbp = mbp0 + tt*256;

    f32x4 sca[4], scb[4];
    const int delta = kv0 - q0;
    if (delta <= -128 || delta >= 192){
      #pragma unroll
      for (int kt=0;kt<4;kt++){
        f32x4 mb4 = *reinterpret_cast<const f32x4*>(mbp + kt*64);
        sca[kt] = mb4;
        scb[kt] = mb4;
      }
    } else {
      const int pbase = delta + 63 - (wt*32 + fr) + 128 + g*4;
      f32x4 rr[5];
      #pragma unroll
      for (int j=0;j<5;j++)
        #pragma unroll
        for (int r=0;r<4;r++)
          rr[j][r] = rel_pad[pbase - 16 + j*16 + r];
      #pragma unroll
      for (int kt=0;kt<4;kt++){
        f32x4 mb4 = *reinterpret_cast<const f32x4*>(mbp + kt*64);
        #pragma unroll
        for (int r=0;r<4;r++){
          sca[kt][r] = rr[kt+1][r] + mb4[r];
          scb[kt][r] = rr[kt][r]   + mb4[r];
        }
      }
    }

    __builtin_amdgcn_s_setprio(1);
    #pragma unroll
    for (int kt=0;kt<4;kt++){
      #pragma unroll
      for (int f=0;f<2;f++){
        short8 kf = *reinterpret_cast<const short8*>(kp[f] + (kt*2048 + BUFL*8192));
        sca[kt] = __builtin_amdgcn_mfma_f32_16x16x32_bf16(kf, qfa[f], sca[kt], 0,0,0);
        scb[kt] = __builtin_amdgcn_mfma_f32_16x16x32_bf16(kf, qfb[f], scb[kt], 0,0,0);
      }
    }
    __builtin_amdgcn_s_setprio(0);

    short4v paa[4], pab[4];
    {
      const float tmax = tmax16(sca);
      if (!__all(tmax <= mruna + 8.f)){
        float tm = fmaxf(tmax, __shfl_xor(tmax, 16));
        tm = fmaxf(tm, __shfl_xor(tm, 32));
        const float mnew = fmaxf(mruna, tm);
        const float corr = EXP2(mruna - mnew);
        lruna *= corr;
        #pragma unroll
        for (int dt=0;dt<4;dt++)
          #pragma unroll
          for (int r=0;r<4;r++) ctxa[dt][r] *= corr;
        mruna = mnew;
      }
      float psum = 0.f;
      #pragma unroll
      for (int kt=0;kt<4;kt++){
        float p0 = EXP2(sca[kt][0] - mruna);
        float p1 = EXP2(sca[kt][1] - mruna);
        float p2 = EXP2(sca[kt][2] - mruna);
        float p3 = EXP2(sca[kt][3] - mruna);
        psum += (p0 + p1) + (p2 + p3);
        union { short4v s; __hip_bfloat162 hh[2]; } u;
        u.hh[0] = __float22bfloat162_rn(make_float2(p0, p1));
        u.hh[1] = __float22bfloat162_rn(make_float2(p2, p3));
        paa[kt] = u.s;
      }
      lruna += psum;
    }
    {
      const float tmax = tmax16(scb);
      if (!__all(tmax <= mrunb + 8.f)){
        float tm = fmaxf(tmax, __shfl_xor(tmax, 16));
        tm = fmaxf(tm, __shfl_xor(tm, 32));
        const float mnew = fmaxf(mrunb, tm);
        const float corr = EXP2(mrunb - mnew);
        lrunb *= corr;
        #pragma unroll
        for (int dt=0;dt<4;dt++)
          #pragma unroll
          for (int r=0;r<4;r++) ctxb[dt][r] *= corr;
        mrunb = mnew;
      }
      float psum = 0.f;
      #pragma unroll
      for (int kt=0;kt<4;kt++){
        float p0 = EXP2(scb[kt][0] - mrunb);
        float p1 = EXP2(scb[kt][1] - mrunb);
        float p2 = EXP2(scb[kt][2] - mrunb);
        float p3 = EXP2(scb[kt][3] - mrunb);
        psum += (p0 + p1) + (p2 + p3);
        union { short4v s; __hip_bfloat162 hh[2]; } u;
        u.hh[0] = __float22bfloat162_rn(make_float2(p0, p1));
        u.hh[1] = __float22bfloat162_rn(make_float2(p2, p3));
        pab[kt] = u.s;
      }
      lrunb += psum;
    }

    __builtin_amdgcn_s_setprio(1);
#if HAVE_MFMA16
    #pragma unroll
    for (int dt=0;dt<4;dt++){
      #pragma unroll
      for (int kt=0;kt<4;kt++){
        short4v va = *reinterpret_cast<const short4v*>(vp[kt] + (dt*2048 + BUFL*8192));
        ctxa[dt] = __builtin_amdgcn_mfma_f32_16x16x16bf16_1k(va, paa[kt], ctxa[dt], 0,0,0);
        ctxb[dt] = __builtin_amdgcn_mfma_f32_16x16x16bf16_1k(va, pab[kt], ctxb[dt], 0,0,0);
      }
    }
#else
    const char* vsb = lds0 + 32768 + team*16384 + BUFL*8192;
    #pragma unroll
    for (int f=0;f<2;f++){
      union { short8 s8; unsigned u[4]; } bfa, bfb;
      #pragma unroll
      for (int m=0;m<4;m++){
        const int srcl = ((g&1)*2 + (m>>1))*16 + fr;
        union { short4v s; unsigned u[2]; } ca0, ca1, cb0, cb1;
        ca0.s = paa[f*2+0]; ca1.s = paa[f*2+1];
        cb0.s = pab[f*2+0]; cb1.s = pab[f*2+1];
        unsigned a0 = __shfl((int)ca0.u[m&1], srcl);
        unsigned a1 = __shfl((int)ca1.u[m&1], srcl);
        bfa.u[m] = (g >> 1) ? a1 : a0;
        unsigned b0 = __shfl((int)cb0.u[m&1], srcl);
        unsigned b1 = __shfl((int)cb1.u[m&1], srcl);
        bfb.u[m] = (g >> 1) ? b1 : b0;
      }
      #pragma unroll
      for (int dt=0;dt<4;dt++){
        const int dr = dt*16 + fr;
        const int vswz = (dr & 7) << 4;
        short8 va = *reinterpret_cast<const short8*>(
            vsb + dr*128 + ((g*16 + f*64) ^ vswz));
        ctxa[dt] = __builtin_amdgcn_mfma_f32_16x16x32_bf16(va, bfa.s8, ctxa[dt], 0,0,0);
        ctxb[dt] = __builtin_amdgcn_mfma_f32_16x16x32_bf16(va, bfb.s8, ctxb[dt], 0,0,0);
      }
    }
#endif
    __builtin_amdgcn_s_setprio(0);

    asm volatile("" ::: "memory");
    __builtin_amdgcn_s_barrier();
  };

  const int kvbase = team * 512;
  __syncthreads();                       // fills visible; vmcnt=0
  stage(0, kvbase);
  stage(1, kvbase + 64);

  for (int t = 0; t < 6; t += 2){
    tile_step(ic<0>{}, ic<4>{}, kvbase + t*64,     t);
    stage(0, kvbase + (t+2)*64);
    tile_step(ic<1>{}, ic<4>{}, kvbase + (t+1)*64, t+1);
    stage(1, kvbase + (t+3)*64);
  }
  tile_step(ic<0>{}, ic<4>{}, kvbase + 6*64, 6);
  tile_step(ic<1>{}, ic<0>{}, kvbase + 7*64, 7);
  asm volatile("" ::: "memory");

  lruna += __shfl_xor(lruna, 16);
  lruna += __shfl_xor(lruna, 32);
  lrunb += __shfl_xor(lrunb, 16);
  lrunb += __shfl_xor(lrunb, 32);

  float* mctx = (float*)&kvbuf[0][0][0][0][0];
  const int rowA = wt*32 + fr, rowB = rowA + 16;
  if (team == 1){
    #pragma unroll
    for (int dt=0;dt<4;dt++){
      *reinterpret_cast<f32x4*>(&mctx[rowA*72 + dt*16 + g*4]) = ctxa[dt];
      *reinterpret_cast<f32x4*>(&mctx[rowB*72 + dt*16 + g*4]) = ctxb[dt];
    }
    ml[rowA][0] = mruna; ml[rowA][1] = lruna;
    ml[rowB][0] = mrunb; ml[rowB][1] = lrunb;
  }
  __syncthreads();
  if (team == 0){
    {
      const float m1 = ml[rowA][0], l1 = ml[rowA][1];
      const float m  = fmaxf(mruna, m1);
      const float s0 = EXP2(mruna - m), s1 = EXP2(m1 - m);
      const float rl = 1.f / (lruna*s0 + l1*s1);
      #pragma unroll
      for (int dt=0;dt<4;dt++){
        f32x4 c1 = *reinterpret_cast<const f32x4*>(&mctx[rowA*72 + dt*16 + g*4]);
        short4v o;
        #pragma unroll
        for (int r=0;r<4;r++) o[r] = f2b((ctxa[dt][r]*s0 + c1[r]*s1) * rl);
        *reinterpret_cast<short4v*>(
            Ctx + (size_t)(b*SEQ + qa)*D_MODEL + h*D_KK + dt*16 + g*4) = o;
      }
    }
    {
      const float m1 = ml[rowB][0], l1 = ml[rowB][1];
      const float m  = fmaxf(mrunb, m1);
      const float s0 = EXP2(mrunb - m), s1 = EXP2(m1 - m);
      const float rl = 1.f / (lrunb*s0 + l1*s1);
      #pragma unroll
      for (int dt=0;dt<4;dt++){
        f32x4 c1 = *reinterpret_cast<const f32x4*>(&mctx[rowB*72 + dt*16 + g*4]);
        short4v o;
        #pragma unroll
        for (int r=0;r<4;r++) o[r] = f2b((ctxb[dt][r]*s0 + c1[r]*s1) * rl);
        *reinterpret_cast<short4v*>(
            Ctx + (size_t)(b*SEQ + qb)*D_MODEL + h*D_KK + dt*16 + g*4) = o;
      }
    }
  }
}

// ---------------- launch ----------------
extern "C" void kernel_launch(void* const* d_in, const int* in_sizes, int n_in,
                              void* d_out, int out_size, void* d_ws, size_t ws_size,
                              hipStream_t stream) {
  const float* x    = (const float*)d_in[0];
  const int*   mask = (const int*)  d_in[1];
  const float* wq   = (const float*)d_in[2];
  const float* bq   = (const float*)d_in[3];
  const float* wk   = (const float*)d_in[4];
  const float* bk   = (const float*)d_in[5];
  const float* wv   = (const float*)d_in[6];
  const float* bv   = (const float*)d_in[7];
  const float* wo   = (const float*)d_in[8];
  const float* bo   = (const float*)d_in[9];
  const float* rel  = (const float*)d_in[10];

  const size_t NX = (size_t)NTOK * D_MODEL;      // 4194304
  const size_t NW = (size_t)D_MODEL * D_MODEL;   // 1048576
  if (ws_size < (NX + 4*NW + 4*NX) * sizeof(short)) return;
  short* xb   = (short*)d_ws;
  short* wqb  = xb  + NX;
  short* wkb  = wqb + NW;
  short* wvb  = wkb + NW;
  short* wob  = wvb + NW;
  short* Qb   = wob + NW;   // holds Q * 0.125 * log2e (prescaled)
  short* Kb   = Qb  + NX;
  short* Vtg  = Kb  + NX;   // V transposed per head: [B*H][64][SEQ]
  short* Ctxb = Vtg + NX;

  cvt_all_kernel<<<8192, 256, 0, stream>>>(x, wq, wk, wv, wo, xb);

  qkv_gemm_kernel<<<512, 256, 0, stream>>>(
      xb, wqb, wkb, wvb, bq, bk, bv, Qb, Kb, Vtg);

  attn_kernel<<<512, 512, 0, stream>>>(Qb, Kb, Vtg, mask, rel, Ctxb);

  out_gemm_kernel<<<512, 256, 0, stream>>>(Ctxb, wob, bo, (float*)d_out);
}

// Round 19
// 99.443 us; speedup vs baseline: 1.1114x; 1.1114x over previous
//
#include <hip/hip_runtime.h>
#include <hip/hip_bf16.h>

typedef __attribute__((ext_vector_type(8))) short short8;
typedef __attribute__((ext_vector_type(4))) short short4v;
typedef __attribute__((ext_vector_type(4))) float f32x4;

#define D_MODEL 1024
#define N_HEADS 16
#define D_KK 64
#define BATCH 4
#define SEQ 1024
#define NTOK (BATCH*SEQ)

#define LOG2E  1.44269504f
#define SCALE2 (0.125f * 1.44269504f)
#define NEGBIG (-1.44269504e9f)

#if __has_builtin(__builtin_amdgcn_mfma_f32_16x16x16bf16_1k)
#define HAVE_MFMA16 1
#else
#define HAVE_MFMA16 0
#endif

#if __has_builtin(__builtin_amdgcn_exp2f)
#define EXP2(x) __builtin_amdgcn_exp2f(x)
#else
#define EXP2(x) exp2f(x)
#endif

template<int N> struct ic { static constexpr int value = N; };

// round-to-nearest-even f32 -> bf16 (bit pattern in short)
__device__ __forceinline__ short f2b(float f){
  unsigned u = __float_as_uint(f);
  u += 0x7fffu + ((u >> 16) & 1u);
  return (short)(u >> 16);
}

__device__ __forceinline__ void gl2lds16(const void* g, void* l){
  __builtin_amdgcn_global_load_lds(
      (const __attribute__((address_space(1))) void*)g,
      (__attribute__((address_space(3))) void*)l, 16, 0, 0);
}

__device__ __forceinline__ float max3f(float a, float b, float c){
  float d; asm("v_max3_f32 %0, %1, %2, %3" : "=v"(d) : "v"(a), "v"(b), "v"(c)); return d;
}
__device__ __forceinline__ float tmax16(const f32x4* sc){
  float t = max3f(sc[0][0], sc[0][1], sc[0][2]);
  t = max3f(t, sc[0][3], sc[1][0]);
  t = max3f(t, sc[1][1], sc[1][2]);
  t = max3f(t, sc[1][3], sc[2][0]);
  t = max3f(t, sc[2][1], sc[2][2]);
  t = max3f(t, sc[2][3], sc[3][0]);
  t = max3f(t, sc[3][1], sc[3][2]);
  return fmaxf(t, sc[3][3]);
}

// ---------------- fused f32 -> bf16 conversion (x, wq, wk, wv, wo) ----------
// 8 elems/thread (segment sizes are multiples of 8 -> no straddle).
__global__ __launch_bounds__(256) void cvt_all_kernel(
    const float* __restrict__ x,  const float* __restrict__ wq,
    const float* __restrict__ wk, const float* __restrict__ wv,
    const float* __restrict__ wo, short* __restrict__ dst)
{
  const size_t NX = (size_t)NTOK * D_MODEL;
  const size_t NW = (size_t)D_MODEL * D_MODEL;
  size_t e = ((size_t)blockIdx.x * 256 + threadIdx.x) * 8;
  const float* s;
  size_t off;
  if      (e < NX)        { s = x;  off = e; }
  else if (e < NX +   NW) { s = wq; off = e - NX; }
  else if (e < NX + 2*NW) { s = wk; off = e - NX -   NW; }
  else if (e < NX + 3*NW) { s = wv; off = e - NX - 2*NW; }
  else                    { s = wo; off = e - NX - 3*NW; }
  f32x4 v0 = *reinterpret_cast<const f32x4*>(s + off);
  f32x4 v1 = *reinterpret_cast<const f32x4*>(s + off + 4);
  short8 o;
  o[0]=f2b(v0[0]); o[1]=f2b(v0[1]); o[2]=f2b(v0[2]); o[3]=f2b(v0[3]);
  o[4]=f2b(v1[0]); o[5]=f2b(v1[1]); o[6]=f2b(v1[2]); o[7]=f2b(v1[3]);
  *reinterpret_cast<short8*>(dst + e) = o;
}

// ---------------- z-fused QKV GEMM (round-17 proven version) ---------------
// 512 blocks x 256 thr, XCD-grouped, tile 128x64, 4 waves (2x2, 64x32 each).
// A-panel staged ONCE per K-step and reused for Wq/Wk/Wv: 48 MFMA per wave
// per barrier-pair, DS ratio 0.42 reads/MFMA, A L2-traffic /3. Single-
// buffered 40 KB LDS (round-18 dbuf = 80 KB -> 1 blk/CU -> regression).
__global__ __launch_bounds__(256) void qkv_gemm_kernel(
    const short* __restrict__ X,
    const short* __restrict__ Wq, const short* __restrict__ Wk, const short* __restrict__ Wv,
    const float* __restrict__ bq, const float* __restrict__ bk, const float* __restrict__ bv,
    short* __restrict__ Q, short* __restrict__ K, short* __restrict__ V)
{
  __shared__ short As[128*64];      // 16 KB
  __shared__ short Bs[3][64*64];    // 24 KB
  const int bid = blockIdx.x;
  const int xcd = bid & 7, s = bid >> 3;        // s in [0,64)
  const int bn0 = (s >> 2) * 64;                 // 16 N-tiles
  const int bm0 = (xcd * 4 + (s & 3)) * 128;     // 4 M-tiles per XCD

  const int tid = threadIdx.x, lane = tid & 63, w = tid >> 6;
  const int wr = w >> 1, wc = w & 1;             // wave-tile 64x32
  const int srow = lane >> 3;
  const int scol = ((lane & 7) ^ srow) * 8;
  const int fr = lane & 15, g = lane >> 4;

  const short* const Wz[3] = {Wq, Wk, Wv};

  f32x4 acc[3][4][2];
  #pragma unroll
  for (int z=0;z<3;z++)
    #pragma unroll
    for (int m=0;m<4;m++)
      #pragma unroll
      for (int n=0;n<2;n++) acc[z][m][n] = (f32x4){0.f,0.f,0.f,0.f};

  for (int k0 = 0; k0 < D_MODEL; k0 += 64){
    __syncthreads();
    #pragma unroll
    for (int i=0;i<4;i++){                       // A: 16 chunks, 4/wave
      const int c = w*4 + i;
      gl2lds16(X + (size_t)(bm0 + c*8 + srow)*D_MODEL + k0 + scol, &As[c*8*64]);
    }
    #pragma unroll
    for (int z=0;z<3;z++)
      #pragma unroll
      for (int i=0;i<2;i++){                     // B: 8 chunks per z, 2/wave
        const int c = w*2 + i;
        gl2lds16(Wz[z] + (size_t)(bn0 + c*8 + srow)*D_MODEL + k0 + scol, &Bs[z][c*8*64]);
      }
    __syncthreads();
    #pragma unroll
    for (int f=0; f<2; f++){
      short8 af[4];
      #pragma unroll
      for (int m=0;m<4;m++){
        const int rr = wr*64 + m*16 + fr;
        af[m] = *reinterpret_cast<const short8*>(
            (const char*)As + rr*128 + ((g*16 + f*64) ^ ((rr&7)<<4)));
      }
      #pragma unroll
      for (int z=0;z<3;z++){
        short8 bfr[2];
        #pragma unroll
        for (int n=0;n<2;n++){
          const int rr = wc*32 + n*16 + fr;
          bfr[n] = *reinterpret_cast<const short8*>(
              (const char*)&Bs[z][0] + rr*128 + ((g*16 + f*64) ^ ((rr&7)<<4)));
        }
        #pragma unroll
        for (int m=0;m<4;m++)
          #pragma unroll
          for (int n=0;n<2;n++)
            acc[z][m][n] = __builtin_amdgcn_mfma_f32_16x16x32_bf16(af[m], bfr[n], acc[z][m][n], 0,0,0);
      }
    }
  }

  // epilogue: z=0 -> Q (prescaled), z=1 -> K, z=2 -> V transposed per head
  #pragma unroll
  for (int z=0;z<3;z++){
    const float* bias = (z==0) ? bq : (z==1) ? bk : bv;
    #pragma unroll
    for (int n=0;n<2;n++){
      const int col = bn0 + wc*32 + n*16 + fr;
      const float bv_ = bias[col];
      #pragma unroll
      for (int m=0;m<4;m++){
        const int row0 = bm0 + wr*64 + m*16 + g*4;
        if (z == 2){
          const int hh = col >> 6, dd = col & 63;
          const int bb = row0 >> 10, ss = row0 & 1023;
          short4v o;
          #pragma unroll
          for (int r=0;r<4;r++) o[r] = f2b(acc[z][m][n][r] + bv_);
          *reinterpret_cast<short4v*>(
              V + ((size_t)(bb*N_HEADS+hh)*D_KK + dd)*SEQ + ss) = o;
        } else {
          short* O = (z==0) ? Q : K;
          #pragma unroll
          for (int r=0;r<4;r++){
            float v = acc[z][m][n][r] + bv_;
            if (z == 0) v *= SCALE2;
            O[(size_t)(row0+r)*D_MODEL + col] = f2b(v);
          }
        }
      }
    }
  }
}

// ---------------- GEMM body, 4-wave (out_gemm) ----------------------------
template<int BN, int MODE, bool PRESC>
__device__ __forceinline__ void gemm_bt_body(const short* __restrict__ A,
    const short* __restrict__ W, const float* __restrict__ bias,
    void* __restrict__ Cout, int N, int K, int bm0, int bn0,
    short* AsB, short* BsB)
{
  constexpr int NF = BN / 32;
  const int tid = threadIdx.x, lane = tid & 63, w = tid >> 6;
  const int wr = w >> 1, wc = w & 1;
  const int srow = lane >> 3;
  const int scol = ((lane & 7) ^ srow) * 8;
  const int fr = lane & 15, g = lane >> 4;

  f32x4 acc[4][NF];
  #pragma unroll
  for (int m=0;m<4;m++)
    #pragma unroll
    for (int n=0;n<NF;n++) acc[m][n] = (f32x4){0.f,0.f,0.f,0.f};

  for (int k0 = 0; k0 < K; k0 += 64){
    __syncthreads();
    #pragma unroll
    for (int i=0;i<4;i++){
      const int c = w*4 + i;
      gl2lds16(A + (size_t)(bm0 + c*8 + srow)*K + k0 + scol, &AsB[c*8*64]);
    }
    #pragma unroll
    for (int i=0;i<NF;i++){
      const int c = w*NF + i;
      gl2lds16(W + (size_t)(bn0 + c*8 + srow)*K + k0 + scol, &BsB[c*8*64]);
    }
    __syncthreads();
    #pragma unroll
    for (int f=0; f<2; f++){
      short8 af[4], bfr[NF];
      #pragma unroll
      for (int m=0;m<4;m++){
        const int rr = wr*64 + m*16 + fr;
        af[m] = *reinterpret_cast<const short8*>(
            (const char*)AsB + rr*128 + ((g*16 + f*64) ^ ((rr&7)<<4)));
      }
      #pragma unroll
      for (int n=0;n<NF;n++){
        const int rr = wc*(BN/2) + n*16 + fr;
        bfr[n] = *reinterpret_cast<const short8*>(
            (const char*)BsB + rr*128 + ((g*16 + f*64) ^ ((rr&7)<<4)));
      }
      #pragma unroll
      for (int m=0;m<4;m++)
        #pragma unroll
        for (int n=0;n<NF;n++)
          acc[m][n] = __builtin_amdgcn_mfma_f32_16x16x32_bf16(af[m], bfr[n], acc[m][n], 0,0,0);
    }
  }

  #pragma unroll
  for (int n=0;n<NF;n++){
    const int col = bn0 + wc*(BN/2) + n*16 + fr;
    const float bv = bias[col];
    #pragma unroll
    for (int m=0;m<4;m++){
      const int row0 = bm0 + wr*64 + m*16 + g*4;
      #pragma unroll
      for (int r=0;r<4;r++){
        float v = acc[m][n][r] + bv;
        if (PRESC) v *= SCALE2;
        if (MODE == 1) ((float*)Cout)[(size_t)(row0+r)*N + col] = v;
        else           ((short*)Cout)[(size_t)(row0+r)*N + col] = f2b(v);
      }
    }
  }
}

// 512 blocks x 256 threads, XCD-grouped.
__global__ __launch_bounds__(256) void out_gemm_kernel(
    const short* __restrict__ Ctx, const short* __restrict__ Wo,
    const float* __restrict__ bo, float* __restrict__ Out)
{
  __shared__ short As[128*64];
  __shared__ short Bs[64*64];
  const int bid = blockIdx.x;
  const int xcd = bid & 7, s = bid >> 3;   // s in [0,64)
  const int bn0 = (s >> 2) * 64;            // 16 N-tiles
  const int bm0 = (xcd * 4 + (s & 3)) * 128;
  gemm_bt_body<64,1,false>(Ctx, Wo, bo, Out, D_MODEL, D_MODEL, bm0, bn0, As, Bs);
}

// ---------------- flash attention (round-15/17 proven version) ------------
__global__ __launch_bounds__(512, 2) void attn_kernel(
    const short* __restrict__ Qb, const short* __restrict__ Kb,
    const short* __restrict__ Vtg, const int* __restrict__ mask,
    const float* __restrict__ rel_table, short* __restrict__ Ctx)
{
  const int bid = blockIdx.x;
  const int xcd = bid & 7, slot = bid >> 3;
  const int bh = xcd * 8 + (slot >> 3);      // 8 (b,h) groups per XCD
  const int qt = slot & 7;                   // 8 q-tiles of 128 rows
  const int b = bh >> 4, h = bh & 15;
  const int q0 = qt * 128;
  const int tid = threadIdx.x, lane = tid & 63, w = tid >> 6;
  const int team = w >> 2, wt = w & 3;
  const int fr = lane & 15, g = lane >> 4;

  __shared__ short kvbuf[2][2][2][64][64];  // [K/V][team][buf][row][64], swizzled
  __shared__ float rel_pad[384];            // rel*log2e, clamp baked, offset +128
  __shared__ float mb_all[2][8][64];        // per-team per-tile mask+cb bias
  __shared__ float ml[128][2];

  for (int i = tid; i < 384; i += 512){
    int d = i - 128;
    d = d < 0 ? 0 : (d > 126 ? 126 : d);
    rel_pad[i] = rel_table[d * N_HEADS + h] * LOG2E;
  }
  const float cb_lo = rel_table[0*N_HEADS + h]   * LOG2E;
  const float cb_hi = rel_table[126*N_HEADS + h] * LOG2E;

  for (int e = tid; e < 1024; e += 512){
    const int tm = e >> 9, tt = (e >> 6) & 7, i = e & 63;
    const int kvt = tm*512 + tt*64;
    const int delta = kvt - q0;
    const bool far = (delta <= -128 || delta >= 192);
    const float cb = far ? (delta > 0 ? cb_hi : cb_lo) : 0.f;
    mb_all[tm][tt][i] = mask[b*SEQ + kvt + i] ? cb : NEGBIG;
  }

  const short* Qg = Qb + (size_t)b*SEQ*D_MODEL + h*D_KK;
  const short* Kg = Kb + (size_t)b*SEQ*D_MODEL + h*D_KK;
  const short* Vg = Vtg + (size_t)bh*D_KK*SEQ;

  const int qa = q0 + wt*32 + fr;
  const int qb = qa + 16;
  short8 qfa[2], qfb[2];
  #pragma unroll
  for (int f=0; f<2; f++){
    qfa[f] = *reinterpret_cast<const short8*>(Qg + (size_t)qa*D_MODEL + g*8 + f*32);
    qfb[f] = *reinterpret_cast<const short8*>(Qg + (size_t)qb*D_MODEL + g*8 + f*32);
  }

  const char* lds0 = (const char*)kvbuf;
  const int swzb = (fr & 7) << 4;
  const char* kp[2];
  #pragma unroll
  for (int f=0; f<2; f++)
    kp[f] = lds0 + team*16384 + fr*128 + ((g*16 + f*64) ^ swzb);
  const char* vp[4];
  #pragma unroll
  for (int kt=0; kt<4; kt++)
    vp[kt] = lds0 + 32768 + team*16384 + fr*128
           + ((((kt*2 + (g>>1)) ^ (fr&7)) << 4) + (g&1)*8);
  const char* mbp0 = (const char*)mb_all + team*2048 + g*16;

  f32x4 ctxa[4], ctxb[4];
  #pragma unroll
  for (int dt=0; dt<4; dt++){ ctxa[dt] = (f32x4){0.f,0.f,0.f,0.f}; ctxb[dt] = ctxa[dt]; }
  float mruna = -3.0e38f, lruna = 0.f, mrunb = -3.0e38f, lrunb = 0.f;

  const int srow = lane >> 3;
  const int scol = ((lane & 7) ^ srow) * 8;
  auto stage = [&](int buf, int kv0){
    #pragma unroll
    for (int i=0;i<2;i++){
      const int c = wt*2 + i;
      gl2lds16(Kg + (size_t)(kv0 + c*8 + srow)*D_MODEL + scol, &kvbuf[0][team][buf][c*8][0]);
      gl2lds16(Vg + (size_t)(c*8 + srow)*SEQ + kv0 + scol,     &kvbuf[1][team][buf][c*8][0]);
    }
  };

  auto tile_step = [&](auto BUFC, auto VMC, int kv0, int tt) __attribute__((always_inline)) {
    constexpr int BUFL = decltype(BUFC)::value;
    constexpr int VM   = decltype(VMC)::value;

    if constexpr (VM == 4) asm volatile("s_waitcnt vmcnt(4)" ::: "memory");
    else                   asm volatile("s_waitcnt vmcnt(0)" ::: "memory");
    __builtin_amdgcn_s_barrier();
    asm volatile("" ::: "memory");

    const char* mbp = mbp0 + tt*256;

    f32x4 sca[4], scb[4];
    const int delta = kv0 - q0;
    if (delta <= -128 || delta >= 192){
      #pragma unroll
      for (int kt=0;kt<4;kt++){
        f32x4 mb4 = *reinterpret_cast<const f32x4*>(mbp + kt*64);
        sca[kt] = mb4;
        scb[kt] = mb4;
      }
    } else {
      const int pbase = delta + 63 - (wt*32 + fr) + 128 + g*4;
      f32x4 rr[5];
      #pragma unroll
      for (int j=0;j<5;j++)
        #pragma unroll
        for (int r=0;r<4;r++)
          rr[j][r] = rel_pad[pbase - 16 + j*16 + r];
      #pragma unroll
      for (int kt=0;kt<4;kt++){
        f32x4 mb4 = *reinterpret_cast<const f32x4*>(mbp + kt*64);
        #pragma unroll
        for (int r=0;r<4;r++){
          sca[kt][r] = rr[kt+1][r] + mb4[r];
          scb[kt][r] = rr[kt][r]   + mb4[r];
        }
      }
    }

    __builtin_amdgcn_s_setprio(1);
    #pragma unroll
    for (int kt=0;kt<4;kt++){
      #pragma unroll
      for (int f=0;f<2;f++){
        short8 kf = *reinterpret_cast<const short8*>(kp[f] + (kt*2048 + BUFL*8192));
        sca[kt] = __builtin_amdgcn_mfma_f32_16x16x32_bf16(kf, qfa[f], sca[kt], 0,0,0);
        scb[kt] = __builtin_amdgcn_mfma_f32_16x16x32_bf16(kf, qfb[f], scb[kt], 0,0,0);
      }
    }
    __builtin_amdgcn_s_setprio(0);

    short4v paa[4], pab[4];
    {
      const float tmax = tmax16(sca);
      if (!__all(tmax <= mruna + 8.f)){
        float tm = fmaxf(tmax, __shfl_xor(tmax, 16));
        tm = fmaxf(tm, __shfl_xor(tm, 32));
        const float mnew = fmaxf(mruna, tm);
        const float corr = EXP2(mruna - mnew);
        lruna *= corr;
        #pragma unroll
        for (int dt=0;dt<4;dt++)
          #pragma unroll
          for (int r=0;r<4;r++) ctxa[dt][r] *= corr;
        mruna = mnew;
      }
      float psum = 0.f;
      #pragma unroll
      for (int kt=0;kt<4;kt++){
        float p0 = EXP2(sca[kt][0] - mruna);
        float p1 = EXP2(sca[kt][1] - mruna);
        float p2 = EXP2(sca[kt][2] - mruna);
        float p3 = EXP2(sca[kt][3] - mruna);
        psum += (p0 + p1) + (p2 + p3);
        union { short4v s; __hip_bfloat162 hh[2]; } u;
        u.hh[0] = __float22bfloat162_rn(make_float2(p0, p1));
        u.hh[1] = __float22bfloat162_rn(make_float2(p2, p3));
        paa[kt] = u.s;
      }
      lruna += psum;
    }
    {
      const float tmax = tmax16(scb);
      if (!__all(tmax <= mrunb + 8.f)){
        float tm = fmaxf(tmax, __shfl_xor(tmax, 16));
        tm = fmaxf(tm, __shfl_xor(tm, 32));
        const float mnew = fmaxf(mrunb, tm);
        const float corr = EXP2(mrunb - mnew);
        lrunb *= corr;
        #pragma unroll
        for (int dt=0;dt<4;dt++)
          #pragma unroll
          for (int r=0;r<4;r++) ctxb[dt][r] *= corr;
        mrunb = mnew;
      }
      float psum = 0.f;
      #pragma unroll
      for (int kt=0;kt<4;kt++){
        float p0 = EXP2(scb[kt][0] - mrunb);
        float p1 = EXP2(scb[kt][1] - mrunb);
        float p2 = EXP2(scb[kt][2] - mrunb);
        float p3 = EXP2(scb[kt][3] - mrunb);
        psum += (p0 + p1) + (p2 + p3);
        union { short4v s; __hip_bfloat162 hh[2]; } u;
        u.hh[0] = __float22bfloat162_rn(make_float2(p0, p1));
        u.hh[1] = __float22bfloat162_rn(make_float2(p2, p3));
        pab[kt] = u.s;
      }
      lrunb += psum;
    }

    __builtin_amdgcn_s_setprio(1);
#if HAVE_MFMA16
    #pragma unroll
    for (int dt=0;dt<4;dt++){
      #pragma unroll
      for (int kt=0;kt<4;kt++){
        short4v va = *reinterpret_cast<const short4v*>(vp[kt] + (dt*2048 + BUFL*8192));
        ctxa[dt] = __builtin_amdgcn_mfma_f32_16x16x16bf16_1k(va, paa[kt], ctxa[dt], 0,0,0);
        ctxb[dt] = __builtin_amdgcn_mfma_f32_16x16x16bf16_1k(va, pab[kt], ctxb[dt], 0,0,0);
      }
    }
#else
    const char* vsb = lds0 + 32768 + team*16384 + BUFL*8192;
    #pragma unroll
    for (int f=0;f<2;f++){
      union { short8 s8; unsigned u[4]; } bfa, bfb;
      #pragma unroll
      for (int m=0;m<4;m++){
        const int srcl = ((g&1)*2 + (m>>1))*16 + fr;
        union { short4v s; unsigned u[2]; } ca0, ca1, cb0, cb1;
        ca0.s = paa[f*2+0]; ca1.s = paa[f*2+1];
        cb0.s = pab[f*2+0]; cb1.s = pab[f*2+1];
        unsigned a0 = __shfl((int)ca0.u[m&1], srcl);
        unsigned a1 = __shfl((int)ca1.u[m&1], srcl);
        bfa.u[m] = (g >> 1) ? a1 : a0;
        unsigned b0 = __shfl((int)cb0.u[m&1], srcl);
        unsigned b1 = __shfl((int)cb1.u[m&1], srcl);
        bfb.u[m] = (g >> 1) ? b1 : b0;
      }
      #pragma unroll
      for (int dt=0;dt<4;dt++){
        const int dr = dt*16 + fr;
        const int vswz = (dr & 7) << 4;
        short8 va = *reinterpret_cast<const short8*>(
            vsb + dr*128 + ((g*16 + f*64) ^ vswz));
        ctxa[dt] = __builtin_amdgcn_mfma_f32_16x16x32_bf16(va, bfa.s8, ctxa[dt], 0,0,0);
        ctxb[dt] = __builtin_amdgcn_mfma_f32_16x16x32_bf16(va, bfb.s8, ctxb[dt], 0,0,0);
      }
    }
#endif
    __builtin_amdgcn_s_setprio(0);

    asm volatile("" ::: "memory");
    __builtin_amdgcn_s_barrier();
  };

  const int kvbase = team * 512;
  __syncthreads();                       // fills visible; vmcnt=0
  stage(0, kvbase);
  stage(1, kvbase + 64);

  for (int t = 0; t < 6; t += 2){
    tile_step(ic<0>{}, ic<4>{}, kvbase + t*64,     t);
    stage(0, kvbase + (t+2)*64);
    tile_step(ic<1>{}, ic<4>{}, kvbase + (t+1)*64, t+1);
    stage(1, kvbase + (t+3)*64);
  }
  tile_step(ic<0>{}, ic<4>{}, kvbase + 6*64, 6);
  tile_step(ic<1>{}, ic<0>{}, kvbase + 7*64, 7);
  asm volatile("" ::: "memory");

  lruna += __shfl_xor(lruna, 16);
  lruna += __shfl_xor(lruna, 32);
  lrunb += __shfl_xor(lrunb, 16);
  lrunb += __shfl_xor(lrunb, 32);

  float* mctx = (float*)&kvbuf[0][0][0][0][0];
  const int rowA = wt*32 + fr, rowB = rowA + 16;
  if (team == 1){
    #pragma unroll
    for (int dt=0;dt<4;dt++){
      *reinterpret_cast<f32x4*>(&mctx[rowA*72 + dt*16 + g*4]) = ctxa[dt];
      *reinterpret_cast<f32x4*>(&mctx[rowB*72 + dt*16 + g*4]) = ctxb[dt];
    }
    ml[rowA][0] = mruna; ml[rowA][1] = lruna;
    ml[rowB][0] = mrunb; ml[rowB][1] = lrunb;
  }
  __syncthreads();
  if (team == 0){
    {
      const float m1 = ml[rowA][0], l1 = ml[rowA][1];
      const float m  = fmaxf(mruna, m1);
      const float s0 = EXP2(mruna - m), s1 = EXP2(m1 - m);
      const float rl = 1.f / (lruna*s0 + l1*s1);
      #pragma unroll
      for (int dt=0;dt<4;dt++){
        f32x4 c1 = *reinterpret_cast<const f32x4*>(&mctx[rowA*72 + dt*16 + g*4]);
        short4v o;
        #pragma unroll
        for (int r=0;r<4;r++) o[r] = f2b((ctxa[dt][r]*s0 + c1[r]*s1) * rl);
        *reinterpret_cast<short4v*>(
            Ctx + (size_t)(b*SEQ + qa)*D_MODEL + h*D_KK + dt*16 + g*4) = o;
      }
    }
    {
      const float m1 = ml[rowB][0], l1 = ml[rowB][1];
      const float m  = fmaxf(mrunb, m1);
      const float s0 = EXP2(mrunb - m), s1 = EXP2(m1 - m);
      const float rl = 1.f / (lrunb*s0 + l1*s1);
      #pragma unroll
      for (int dt=0;dt<4;dt++){
        f32x4 c1 = *reinterpret_cast<const f32x4*>(&mctx[rowB*72 + dt*16 + g*4]);
        short4v o;
        #pragma unroll
        for (int r=0;r<4;r++) o[r] = f2b((ctxb[dt][r]*s0 + c1[r]*s1) * rl);
        *reinterpret_cast<short4v*>(
            Ctx + (size_t)(b*SEQ + qb)*D_MODEL + h*D_KK + dt*16 + g*4) = o;
      }
    }
  }
}

// ---------------- launch ----------------
extern "C" void kernel_launch(void* const* d_in, const int* in_sizes, int n_in,
                              void* d_out, int out_size, void* d_ws, size_t ws_size,
                              hipStream_t stream) {
  const float* x    = (const float*)d_in[0];
  const int*   mask = (const int*)  d_in[1];
  const float* wq   = (const float*)d_in[2];
  const float* bq   = (const float*)d_in[3];
  const float* wk   = (const float*)d_in[4];
  const float* bk   = (const float*)d_in[5];
  const float* wv   = (const float*)d_in[6];
  const float* bv   = (const float*)d_in[7];
  const float* wo   = (const float*)d_in[8];
  const float* bo   = (const float*)d_in[9];
  const float* rel  = (const float*)d_in[10];

  const size_t NX = (size_t)NTOK * D_MODEL;      // 4194304
  const size_t NW = (size_t)D_MODEL * D_MODEL;   // 1048576
  if (ws_size < (NX + 4*NW + 4*NX) * sizeof(short)) return;
  short* xb   = (short*)d_ws;
  short* wqb  = xb  + NX;
  short* wkb  = wqb + NW;
  short* wvb  = wkb + NW;
  short* wob  = wvb + NW;
  short* Qb   = wob + NW;   // holds Q * 0.125 * log2e (prescaled)
  short* Kb   = Qb  + NX;
  short* Vtg  = Kb  + NX;   // V transposed per head: [B*H][64][SEQ]
  short* Ctxb = Vtg + NX;

  cvt_all_kernel<<<4096, 256, 0, stream>>>(x, wq, wk, wv, wo, xb);

  qkv_gemm_kernel<<<512, 256, 0, stream>>>(
      xb, wqb, wkb, wvb, bq, bk, bv, Qb, Kb, Vtg);

  attn_kernel<<<512, 512, 0, stream>>>(Qb, Kb, Vtg, mask, rel, Ctxb);

  out_gemm_kernel<<<512, 256, 0, stream>>>(Ctxb, wob, bo, (float*)d_out);
}